// Round 1
// baseline (400.191 us; speedup 1.0000x reference)
//
#include <hip/hip_runtime.h>
#include <math.h>

#define T_STEPS 32
#define NB 64      // batch
#define CC 512     // channels
#define AA 32      // cc_acc size

__device__ __forceinline__ float sig_decay(const float* wp) {
    // decay = 1 - sigmoid(w)
    return 1.0f - 1.0f / (1.0f + expf(-wp[0]));
}

// ---------------------------------------------------------------------------
// Front end: transpose + synapse(tau=2) + jeffress(2->32) + LIF(1.5) +
// synapse(sf0) + w_cc(32->1) + IF + synapse(sf1).  One thread per (n,c),
// loops t; all recurrent state in registers.  Writes y7 (T*N, 512).
// ---------------------------------------------------------------------------
__global__ __launch_bounds__(256) void front_kernel(
    const float* __restrict__ x, const float* __restrict__ w_jeff,
    const float* __restrict__ w_cc, const float* __restrict__ w_sf0,
    const float* __restrict__ w_sf1, float* __restrict__ y7)
{
    __shared__ float wj[2 * AA];
    __shared__ float wcc[AA];
    int tid = threadIdx.x;
    if (tid < 2 * AA) wj[tid] = w_jeff[tid];
    if (tid < AA) wcc[tid] = w_cc[tid];
    __syncthreads();

    int g = blockIdx.x * 256 + tid;     // n*CC + c
    int n = g >> 9;
    int c = g & (CC - 1);

    const float inv_lif = 1.0f / 1.5f;
    float d0 = sig_decay(w_sf0);
    float d1 = sig_decay(w_sf1);

    float s0 = 0.f, s1 = 0.f, v6 = 0.f, u1 = 0.f;
    float v[AA], u[AA];
#pragma unroll
    for (int a = 0; a < AA; a++) { v[a] = 0.f; u[a] = 0.f; }

    for (int t = 0; t < T_STEPS; t++) {
        const float* xp = x + (size_t)((t * NB + n) * 2) * CC + c;
        s0 = s0 * 0.5f + xp[0];     // synapse filter, tau=2 (decay 0.5)
        s1 = s1 * 0.5f + xp[CC];
        float acc = 0.f;
#pragma unroll
        for (int a = 0; a < AA; a++) {
            float z  = wj[2 * a] * s0 + wj[2 * a + 1] * s1;
            float vv = v[a] + (z - v[a]) * inv_lif;   // LIF decay_input
            bool  sp = vv >= 1.0f;
            v[a] = sp ? 0.0f : vv;                    // hard reset
            float uu = u[a] * d0 + (sp ? 1.0f : 0.0f);
            u[a] = uu;
            acc += wcc[a] * uu;
        }
        v6 += acc;                                    // IFNode
        bool sp6 = v6 >= 1.0f;
        v6 = sp6 ? 0.0f : v6;
        u1 = u1 * d1 + (sp6 ? 1.0f : 0.0f);           // sf1 filter
        y7[(size_t)(t * NB + n) * CC + c] = u1;
    }
}

// ---------------------------------------------------------------------------
// IF (+ optional synapse filter) applied in-place over buf (T*N, F).
// One thread per (n,f), loop t.  w_sf == nullptr -> emit raw spikes.
// ---------------------------------------------------------------------------
__global__ __launch_bounds__(256) void if_filter_kernel(
    float* __restrict__ buf, const float* __restrict__ w_sf, int F)
{
    int tid = blockIdx.x * 256 + threadIdx.x;   // n*F + f
    const int NF = NB * F;
    bool  filt = (w_sf != nullptr);
    float d = filt ? sig_decay(w_sf) : 0.0f;
    float v = 0.f, u = 0.f;
    for (int t = 0; t < T_STEPS; t++) {
        float zt = buf[(size_t)t * NF + tid];
        v += zt;
        bool sp = v >= 1.0f;
        v = sp ? 0.0f : v;
        float s = sp ? 1.0f : 0.0f;
        if (filt) { u = u * d + s; buf[(size_t)t * NF + tid] = u; }
        else      { buf[(size_t)t * NF + tid] = s; }
    }
}

// ---------------------------------------------------------------------------
// C = A * B^T.  A: (M,K) row-major, B: (N,K) row-major, C: (M,N) row-major.
// 256 threads as 16x16; micro-tile TM x TN per thread.  BK = 16.
// ---------------------------------------------------------------------------
template <int BM, int BN>
__global__ __launch_bounds__(256) void gemm_nt(
    const float* __restrict__ A, const float* __restrict__ B,
    float* __restrict__ C, int M, int N, int K)
{
    constexpr int BK = 16;
    constexpr int TM = BM / 16;
    constexpr int TN = BN / 16;
    __shared__ float As[BK][BM + 4];
    __shared__ float Bs[BK][BN + 4];

    int tid = threadIdx.x;
    int tx = tid & 15;        // col group
    int ty = tid >> 4;        // row group
    int bm = blockIdx.y * BM;
    int bn = blockIdx.x * BN;

    float acc[TM][TN];
#pragma unroll
    for (int i = 0; i < TM; i++)
#pragma unroll
        for (int j = 0; j < TN; j++) acc[i][j] = 0.f;

    constexpr int A_LOADS = BM * BK / (256 * 4);  // float4 per thread
    constexpr int B_LOADS = BN * BK / (256 * 4);

    for (int k0 = 0; k0 < K; k0 += BK) {
        __syncthreads();
#pragma unroll
        for (int i = 0; i < A_LOADS; i++) {
            int idx = i * 256 + tid;
            int row = idx >> 2;           // BK/4 == 4
            int kq  = idx & 3;
            float4 av = *(const float4*)(A + (size_t)(bm + row) * K + k0 + kq * 4);
            As[kq * 4 + 0][row] = av.x;
            As[kq * 4 + 1][row] = av.y;
            As[kq * 4 + 2][row] = av.z;
            As[kq * 4 + 3][row] = av.w;
        }
#pragma unroll
        for (int i = 0; i < B_LOADS; i++) {
            int idx = i * 256 + tid;
            int row = idx >> 2;
            int kq  = idx & 3;
            float4 bv = *(const float4*)(B + (size_t)(bn + row) * K + k0 + kq * 4);
            Bs[kq * 4 + 0][row] = bv.x;
            Bs[kq * 4 + 1][row] = bv.y;
            Bs[kq * 4 + 2][row] = bv.z;
            Bs[kq * 4 + 3][row] = bv.w;
        }
        __syncthreads();
#pragma unroll
        for (int kk = 0; kk < BK; kk++) {
            float ar[TM], br[TN];
#pragma unroll
            for (int i = 0; i < TM; i++) ar[i] = As[kk][ty * TM + i];
#pragma unroll
            for (int j = 0; j < TN; j++) br[j] = Bs[kk][tx * TN + j];
#pragma unroll
            for (int i = 0; i < TM; i++)
#pragma unroll
                for (int j = 0; j < TN; j++) acc[i][j] += ar[i] * br[j];
        }
    }

#pragma unroll
    for (int i = 0; i < TM; i++) {
        float* cp = C + (size_t)(bm + ty * TM + i) * N + bn + tx * TN;
#pragma unroll
        for (int j = 0; j < TN; j += 4) {
            float4 o;
            o.x = acc[i][j + 0]; o.y = acc[i][j + 1];
            o.z = acc[i][j + 2]; o.w = acc[i][j + 3];
            *(float4*)(cp + j) = o;
        }
    }
}

// ---------------------------------------------------------------------------
// Final: out[t,n] = cumsum_t( dot(y15[t,n,:512], W_out) + b ).
// One wave (64 threads) per n.
// ---------------------------------------------------------------------------
__global__ __launch_bounds__(64) void final_kernel(
    const float* __restrict__ y15, const float* __restrict__ W_out,
    const float* __restrict__ b_out, float* __restrict__ out)
{
    int n = blockIdx.x;
    int lane = threadIdx.x;
    float w[8];
#pragma unroll
    for (int j = 0; j < 8; j++) w[j] = W_out[lane + j * 64];
    float b = b_out[0];
    float cum = 0.f;
    for (int t = 0; t < T_STEPS; t++) {
        const float* yp = y15 + (size_t)(t * NB + n) * 512;
        float p = 0.f;
#pragma unroll
        for (int j = 0; j < 8; j++) p += yp[lane + j * 64] * w[j];
#pragma unroll
        for (int off = 32; off > 0; off >>= 1) p += __shfl_down(p, off);
        if (lane == 0) {
            cum += p + b;
            out[t * NB + n] = cum;
        }
    }
}

extern "C" void kernel_launch(void* const* d_in, const int* in_sizes, int n_in,
                              void* d_out, int out_size, void* d_ws, size_t ws_size,
                              hipStream_t stream) {
    (void)in_sizes; (void)n_in; (void)out_size; (void)ws_size;
    const float* x      = (const float*)d_in[0];
    const float* w_jeff = (const float*)d_in[1];
    const float* w_cc   = (const float*)d_in[2];
    const float* w_sf0  = (const float*)d_in[3];
    const float* W1     = (const float*)d_in[4];
    const float* w_sf1  = (const float*)d_in[5];
    const float* W2     = (const float*)d_in[6];
    const float* w_sf2  = (const float*)d_in[7];
    const float* W3     = (const float*)d_in[8];
    const float* w_sf3  = (const float*)d_in[9];
    const float* W_out  = (const float*)d_in[10];
    const float* b_out  = (const float*)d_in[11];
    float* out = (float*)d_out;

    const int M = T_STEPS * NB;                 // 2048
    float* y7 = (float*)d_ws;                   // (2048, 512)
    float* z1 = y7 + (size_t)M * 512;           // (2048, 2048)
    float* z2 = z1 + (size_t)M * 2048;          // (2048, 1024)
    float* z3 = z2 + (size_t)M * 1024;          // (2048, 512)

    // 1. front end -> y7 (filtered input to W1)
    front_kernel<<<NB * CC / 256, 256, 0, stream>>>(x, w_jeff, w_cc, w_sf0, w_sf1, y7);

    // 2. z1 = y7 @ W1^T   (2048x512)x(2048x512)^T -> (2048,2048)
    gemm_nt<128, 64><<<dim3(2048 / 64, 2048 / 128), 256, 0, stream>>>(y7, W1, z1, M, 2048, 512);

    // 3. IF + filter(sf2) in place on z1
    if_filter_kernel<<<NB * 2048 / 256, 256, 0, stream>>>(z1, w_sf2, 2048);

    // 4. z2 = z1 @ W2^T -> (2048,1024)
    gemm_nt<64, 64><<<dim3(1024 / 64, 2048 / 64), 256, 0, stream>>>(z1, W2, z2, M, 1024, 2048);

    // 5. IF + filter(sf3)
    if_filter_kernel<<<NB * 1024 / 256, 256, 0, stream>>>(z2, w_sf3, 1024);

    // 6. z3 = z2 @ W3^T -> (2048,512)
    gemm_nt<64, 64><<<dim3(512 / 64, 2048 / 64), 256, 0, stream>>>(z2, W3, z3, M, 512, 1024);

    // 7. IF (raw spikes)
    if_filter_kernel<<<NB * 512 / 256, 256, 0, stream>>>(z3, nullptr, 512);

    // 8. final dot + bias + cumsum
    final_kernel<<<NB, 64, 0, stream>>>(z3, W_out, b_out, out);
}